// Round 7
// baseline (864.566 us; speedup 1.0000x reference)
//
#include <hip/hip_runtime.h>
#include <math.h>

#define MQ 512           // states q
#define ML 512           // sequence length L
#define MS 26            // symbols
#define MB 32            // batch
#define MM 2             // models
#define NPOST (MM*MB*ML*MQ)   // 16777216

// ws layout (float slots)
#define OFF_A    0                               // MM*MQ*MQ fp32 prob A
#define OFF_AQ8  (OFF_A + MM*MQ*MQ)              // i8-packed A  [m][128 ip][512 j] dwords
#define OFF_ATQ8 (OFF_AQ8 + MM*128*MQ)           // i8-packed AT
#define OFF_CP   (OFF_ATQ8 + MM*128*MQ)          // col partial maxes [m][16][512]
#define OFF_ROWM (OFF_CP + MM*16*MQ)             // row maxes [m][512]
#define OFF_SCA  (OFF_ROWM + MM*MQ)              // 127/colmax
#define OFF_INVA (OFF_SCA + MM*MQ)               // colmax/127
#define OFF_SCT  (OFF_INVA + MM*MQ)              // 127/rowmax
#define OFF_INVT (OFF_SCT + MM*MQ)               // rowmax/127
#define OFF_B    (OFF_INVT + MM*MQ)
#define OFF_INIT (OFF_B + MM*MQ*MS)
#define OFF_E    (OFF_INIT + MM*MQ)
#define OFF_P1   (OFF_E + NPOST)
#define OFF_LL   (OFF_P1 + NPOST)

#if __has_builtin(__builtin_amdgcn_sdot4)
#define SDOT4(a,b,c) __builtin_amdgcn_sdot4((int)(a),(int)(b),(c),false)
#else
static __device__ __forceinline__ int SDOT4(unsigned a, unsigned b, int c){
  #pragma unroll
  for (int k=0;k<4;++k){
    int av = (int)((a >> (8*k)) & 0xffu); av = (av<<24)>>24;
    int bv = (int)((b >> (8*k)) & 0xffu); bv = (bv<<24)>>24;
    c += av*bv;
  }
  return c;
}
#endif

// ---------------- VALU cross-lane primitives (no LDS pipe) ----------------
#if __has_builtin(__builtin_amdgcn_mov_dpp)
#define DPPF(x, ctrl) __uint_as_float((unsigned)__builtin_amdgcn_mov_dpp(      \
    (int)__float_as_uint(x), (ctrl), 0xF, 0xF, true))
#define HAVE_DPP 1
#else
#define HAVE_DPP 0
#endif

#if __has_builtin(__builtin_amdgcn_permlane16_swap)
static __device__ __forceinline__ float pl16crossf(float x, int lane) {
    unsigned xi = __float_as_uint(x);
    auto r = __builtin_amdgcn_permlane16_swap(xi, xi, false, false);
    return __uint_as_float((lane & 16) ? r[0] : r[1]);
}
static __device__ __forceinline__ float pl16maxf(float x) {
    unsigned xi = __float_as_uint(x);
    auto r = __builtin_amdgcn_permlane16_swap(xi, xi, false, false);
    return fmaxf(__uint_as_float(r[0]), __uint_as_float(r[1]));
}
#else
static __device__ __forceinline__ float pl16crossf(float x, int lane) { (void)lane; return __shfl_xor(x, 16); }
static __device__ __forceinline__ float pl16maxf(float x) { return fmaxf(x, __shfl_xor(x, 16)); }
#endif

#if __has_builtin(__builtin_amdgcn_permlane32_swap)
static __device__ __forceinline__ float pl32maxf(float x) {
    unsigned xi = __float_as_uint(x);
    auto r = __builtin_amdgcn_permlane32_swap(xi, xi, false, false);
    return fmaxf(__uint_as_float(r[0]), __uint_as_float(r[1]));
}
#else
static __device__ __forceinline__ float pl32maxf(float x) { return fmaxf(x, __shfl_xor(x, 32)); }
#endif

#if HAVE_DPP
static __device__ __forceinline__ float xor1f(float x) { return DPPF(x, 0xB1); }  // quad_perm [1,0,3,2]
static __device__ __forceinline__ float xor2f(float x) { return DPPF(x, 0x4E); }  // quad_perm [2,3,0,1]
static __device__ __forceinline__ float ror8f(float x) { return DPPF(x, 0x128); } // xor8 within 16-row
// full-wave max, all-VALU
#define WAVEMAX(X, M) do { float _m = (X);                                    \
  _m = fmaxf(_m, DPPF(_m, 0xB1));   /* xor1 */                                \
  _m = fmaxf(_m, DPPF(_m, 0x4E));   /* xor2 */                                \
  _m = fmaxf(_m, DPPF(_m, 0x124));  /* row_ror:4 */                           \
  _m = fmaxf(_m, DPPF(_m, 0x128));  /* row_ror:8 */                           \
  _m = pl16maxf(_m);                                                          \
  _m = pl32maxf(_m);                                                          \
  M = _m; } while(0)
#else
static __device__ __forceinline__ float xor1f(float x) { return __shfl_xor(x, 1); }
static __device__ __forceinline__ float xor2f(float x) { return __shfl_xor(x, 2); }
static __device__ __forceinline__ float ror8f(float x) { return __shfl_xor(x, 8); }
#define WAVEMAX(X, M) { M = (X);                                              \
  _Pragma("unroll") for (int d = 1; d <= 32; d <<= 1)                         \
    M = fmaxf(M, __shfl_xor(M, d)); }
#endif

// ---------------- row softmax of transition logits -> A (prob domain) ----------------
__global__ void k_softmaxA(const float* __restrict__ tl, float* __restrict__ A) {
    int row = blockIdx.x;                       // m*512 + i
    const float* x = tl + (size_t)row * MQ;
    float* y = A + (size_t)row * MQ;
    int tid = threadIdx.x;                      // 256 threads
    float v0 = x[tid], v1 = x[tid + 256];
    float mx = fmaxf(v0, v1);
    #pragma unroll
    for (int d = 32; d >= 1; d >>= 1) mx = fmaxf(mx, __shfl_xor(mx, d));
    __shared__ float sm[4], ss[4];
    int w = tid >> 6;
    if ((tid & 63) == 0) sm[w] = mx;
    __syncthreads();
    mx = fmaxf(fmaxf(sm[0], sm[1]), fmaxf(sm[2], sm[3]));
    float e0 = expf(v0 - mx), e1 = expf(v1 - mx);
    float s = e0 + e1;
    #pragma unroll
    for (int d = 32; d >= 1; d >>= 1) s += __shfl_xor(s, d);
    if ((tid & 63) == 0) ss[w] = s;
    __syncthreads();
    s = ss[0] + ss[1] + ss[2] + ss[3];
    float inv = 1.0f / s;
    y[tid] = e0 * inv;
    y[tid + 256] = e1 * inv;
}

// ---------------- column partial maxes + row maxes of A ----------------
__global__ void k_amaxc(const float* __restrict__ A, float* __restrict__ colpart,
                        float* __restrict__ rowmax) {
    int g = blockIdx.x, m = blockIdx.y;         // 16 x MM
    int tid = threadIdx.x;                      // 512
    const float* Am = A + (size_t)m*MQ*MQ;
    float cm = 0.f;
    for (int r = 0; r < 32; ++r)
        cm = fmaxf(cm, Am[(size_t)(g*32+r)*MQ + tid]);
    colpart[((size_t)m*16 + g)*MQ + tid] = cm;
    int w = tid >> 6, lane = tid & 63;
    for (int k = 0; k < 4; ++k) {
        int row = g*32 + w*4 + k;
        const float* rp = Am + (size_t)row*MQ;
        float rm = 0.f;
        #pragma unroll
        for (int c = 0; c < 8; ++c) rm = fmaxf(rm, rp[lane + 64*c]);
        #pragma unroll
        for (int d = 1; d <= 32; d <<= 1) rm = fmaxf(rm, __shfl_xor(rm, d));
        if (lane == 0) rowmax[m*MQ + row] = rm;
    }
}

// ---------------- finalize scales ----------------
__global__ void k_amaxr(const float* __restrict__ colpart, const float* __restrict__ rowmax,
                        float* __restrict__ scA, float* __restrict__ invA,
                        float* __restrict__ scT, float* __restrict__ invT) {
    int m = blockIdx.x, j = threadIdx.x;        // MM x 512
    float cm = 0.f;
    #pragma unroll
    for (int g = 0; g < 16; ++g) cm = fmaxf(cm, colpart[((size_t)m*16 + g)*MQ + j]);
    scA[m*MQ + j] = 127.f / cm;  invA[m*MQ + j] = cm * (1.f/127.f);
    float rm = rowmax[m*MQ + j];
    scT[m*MQ + j] = 127.f / rm;  invT[m*MQ + j] = rm * (1.f/127.f);
}

// ---------------- pack A -> i8 dwords [m][ip][j], per-column scale ----------------
__global__ void k_packA8(const float* __restrict__ A, const float* __restrict__ sc,
                         unsigned* __restrict__ Aq) {
    int ip = blockIdx.x, m = blockIdx.y, j = threadIdx.x;  // 128 x MM, 512 thr
    const float* Am = A + (size_t)m*MQ*MQ;
    float s = sc[m*MQ + j];
    unsigned d = 0;
    #pragma unroll
    for (int r = 0; r < 4; ++r) {
        int q = (int)(Am[(size_t)(4*ip+r)*MQ + j] * s + 0.5f);
        d |= ((unsigned)q & 0xffu) << (8*r);
    }
    Aq[((size_t)m*128 + ip)*MQ + j] = d;
}

// ---------------- pack AT -> i8 dwords via 64x64 tile, per-row-of-A scale ----------
__global__ void k_packAT8(const float* __restrict__ A, const float* __restrict__ scT,
                          unsigned* __restrict__ ATq) {
    __shared__ float tile[64][65];
    int ipb = blockIdx.x, jjb = blockIdx.y, m = blockIdx.z;  // 8 x 8 x MM
    int tx = threadIdx.x, ty = threadIdx.y;     // (64,4)
    const float* Am = A + (size_t)m*MQ*MQ;
    for (int r = ty; r < 64; r += 4)
        tile[r][tx] = Am[(size_t)(jjb*64 + r)*MQ + ipb*64 + tx];
    __syncthreads();
    float s = scT[m*MQ + jjb*64 + tx];
    for (int ipl = ty; ipl < 16; ipl += 4) {
        unsigned d = 0;
        #pragma unroll
        for (int r = 0; r < 4; ++r) {
            int q = (int)(tile[tx][4*ipl + r] * s + 0.5f);
            d |= ((unsigned)q & 0xffu) << (8*r);
        }
        ATq[((size_t)m*128 + ipb*16 + ipl)*MQ + jjb*64 + tx] = d;
    }
}

// ---------------- emission softmax (B) + init softmax ----------------
__global__ void k_bprep(const float* __restrict__ emis, const float* __restrict__ initl,
                        float* __restrict__ Bmat, float* __restrict__ initp) {
    int m = blockIdx.x;
    int q = threadIdx.x;                        // 512 threads
    const float* er = emis + ((size_t)(m*MQ) + q) * MS;
    float tv[MS];
    float mx = -1e30f;
    #pragma unroll
    for (int s = 0; s < MS; s++) { tv[s] = er[s]; mx = fmaxf(mx, tv[s]); }
    float sum = 0.f;
    #pragma unroll
    for (int s = 0; s < MS; s++) { tv[s] = expf(tv[s] - mx); sum += tv[s]; }
    float inv = 1.f / sum;
    float* bo = Bmat + ((size_t)(m*MQ) + q) * MS;
    #pragma unroll
    for (int s = 0; s < MS; s++) bo[s] = tv[s] * inv;

    __shared__ float red2[8];
    float v = initl[m*MQ + q];
    float mx2 = v;
    #pragma unroll
    for (int d = 32; d >= 1; d >>= 1) mx2 = fmaxf(mx2, __shfl_xor(mx2, d));
    if ((q & 63) == 0) red2[q >> 6] = mx2;
    __syncthreads();
    mx2 = red2[0];
    #pragma unroll
    for (int k = 1; k < 8; k++) mx2 = fmaxf(mx2, red2[k]);
    float e = expf(v - mx2);
    float s2 = e;
    #pragma unroll
    for (int d = 32; d >= 1; d >>= 1) s2 += __shfl_xor(s2, d);
    __syncthreads();
    if ((q & 63) == 0) red2[q >> 6] = s2;
    __syncthreads();
    s2 = 0.f;
    #pragma unroll
    for (int k = 0; k < 8; k++) s2 += red2[k];
    initp[m*MQ + q] = e / s2;
}

// ---------------- E[m,b,l,q] = sum_s inputs[m,b,l,s]*B[m,q,s] + EPS ----------------
__global__ void k_ekernel(const float* __restrict__ inp, const float* __restrict__ Bmat,
                          float* __restrict__ E) {
    int lc = blockIdx.x, b = blockIdx.y, m = blockIdx.z;
    int tid = threadIdx.x;                      // 512
    __shared__ float Bl[MQ * MS];               // 53KB
    __shared__ float xl[8 * MS];
    for (int k = tid; k < MQ * MS; k += 512) Bl[k] = Bmat[(size_t)m * MQ * MS + k];
    int l0 = lc * 8;
    const float* xin = inp + (((size_t)(m*MB + b) * ML + l0) * MS);
    for (int k = tid; k < 8 * MS; k += 512) xl[k] = xin[k];
    __syncthreads();
    float* Eo = E + (((size_t)(m*MB + b) * ML + l0) * MQ);
    const float* br = Bl + tid * MS;
    for (int l = 0; l < 8; l++) {
        float acc = 1e-16f;
        const float* xr = xl + l * MS;
        #pragma unroll
        for (int s = 0; s < MS; s++) acc = fmaf(br[s], xr[s], acc);
        Eo[l * MQ + tid] = acc;
    }
}

// ---------------- fused fwd/bwd: 128 blocks (dir,m,b) x 1024 threads, i8 dots --------
// R7: 16 waves = 4 waves/SIMD (vs 2).  Per-SIMD SDOT issue is invariant (512 cyc) but
// 4-wave interleave buries the DS-drain, dependent tails, and barrier stagger that
// were ~60% of the 2-wave step wall.  Wave w owns 32 columns; lane: 32-i chunk (ig on
// lane bits {0,1,3,4}) x 8-column octet = 64 SDOT4, A-slice 64 dwords (fits the
// 128-VGPR cap of 16-wave residency).  Chunk (32 i) == producing wave's column range,
// so scale lives in-slot; block normalizer c = 4 VALU xor-maxes.  Butterfly: exact-xor
// scatter dist {1,2,8} + final dist-16 merge (lanes l, l^16 duplicate one column).
// P1/out log+store AFTER the barrier (overlaps next step's DS wait).  Quant per-32.

#define SHM_DYN 81920               // big dyn-LDS pins 1 block/CU
#define CHS 48                      // chunk slot: 32 alpha bytes + 4B scale + pad

// LDS byte offsets
#define AB0   0                     // buffer 0: 16 slots x 48B = 768
#define AB1   768                   // buffer 1
#define REDB  1536                  // loglik scratch (16 f32)

static __device__ __forceinline__ float fastrcp(float x) {
    float r;
    asm("v_rcp_f32 %0, %1" : "=v"(r) : "v"(x));
    return r;
}

#define DOTQ8(P, AD) { u[0]=SDOT4(Ar[(P)*2+0].x,(AD),u[0]); u[1]=SDOT4(Ar[(P)*2+0].y,(AD),u[1]); \
  u[2]=SDOT4(Ar[(P)*2+0].z,(AD),u[2]); u[3]=SDOT4(Ar[(P)*2+0].w,(AD),u[3]);                     \
  u[4]=SDOT4(Ar[(P)*2+1].x,(AD),u[4]); u[5]=SDOT4(Ar[(P)*2+1].y,(AD),u[5]);                     \
  u[6]=SDOT4(Ar[(P)*2+1].z,(AD),u[6]); u[7]=SDOT4(Ar[(P)*2+1].w,(AD),u[7]); }

// i8 matvec over chunk ig (32 i) x 8 columns; per-chunk scale MIG at the int->float
// crossing; exact-xor reduce-scatter over ig bits: dist 1 (j-bit0), dist 2 (j-bit1),
// dist 8 (j-bit2), then dist-16 merge (no scatter).  MV = full column sum for jown;
// lanes l and l^16 both hold jown's value (duplicate pair).
#define MATVEC8(MV, RDB, MIG) do {                                            \
  int u[8];                                                                   \
  _Pragma("unroll") for (int k=0;k<8;k++) u[k]=0;                             \
  const uint4* av4 = (const uint4*)(abm + (RDB) + ig*CHS);                    \
  uint4 a0 = av4[0], a1 = av4[1];                                             \
  DOTQ8(0, a0.x) DOTQ8(1, a0.y) DOTQ8(2, a0.z) DOTQ8(3, a0.w)                 \
  DOTQ8(4, a1.x) DOTQ8(5, a1.y) DOTQ8(6, a1.z) DOTQ8(7, a1.w)                 \
  float fu[8];                                                                \
  _Pragma("unroll") for (int k=0;k<8;k++) fu[k] = (float)u[k] * (MIG);        \
  const int h1 = lane & 1, h2 = (lane >> 1) & 1, h3 = (lane >> 3) & 1;        \
  float v4[4];                                                                \
  _Pragma("unroll") for (int k=0;k<4;k++){                                    \
    float mi = h1 ? fu[2*k+1] : fu[2*k];                                      \
    float ot = h1 ? fu[2*k]   : fu[2*k+1];                                    \
    v4[k] = mi + xor1f(ot); }                                                 \
  float v2[2];                                                                \
  _Pragma("unroll") for (int k=0;k<2;k++){                                    \
    float mi = h2 ? v4[2*k+1] : v4[2*k];                                      \
    float ot = h2 ? v4[2*k]   : v4[2*k+1];                                    \
    v2[k] = mi + xor2f(ot); }                                                 \
  float v1;                                                                   \
  { float mi = h3 ? v2[1] : v2[0];                                            \
    float ot = h3 ? v2[0] : v2[1];                                            \
    v1 = mi + ror8f(ot); }                                                    \
  MV = v1 + pl16crossf(v1, lane);                                             \
} while(0)

// block normalizer: max over the 16 chunk scales (ig lives on lane bits {0,1,3,4})
#define CMAX(C, MIG) { float _c = (MIG);                                      \
  _c = fmaxf(_c, xor1f(_c));                                                  \
  _c = fmaxf(_c, xor2f(_c));                                                  \
  _c = fmaxf(_c, ror8f(_c));                                                  \
  _c = pl16maxf(_c);                                                          \
  C = _c; }

// lgkmcnt-only barrier: LDS writes visible, global stores NOT drained
#define STEP_BARRIER() asm volatile("s_waitcnt lgkmcnt(0)\n\ts_barrier" ::: "memory")

// forward step, compile-time buffers; P1 log+store after the barrier
#define FSTEP(T, RDB, WRB) do {                                               \
    float ev = evn;                                                           \
    int tn = ((T)+1 < ML) ? (T)+1 : ML-1;                                     \
    evn = Eb[(size_t)tn*MQ + jown];                                           \
    float Mig = *(const float*)(abm + (RDB) + ig*CHS + 32);                   \
    float c; CMAX(c, Mig);                                                    \
    float invc = fastrcp(c);                                                  \
    float mv; MATVEC8(mv, RDB, Mig);                                          \
    C += __logf(c);                                                           \
    mv *= rsj126 * invc;                                                      \
    float f = mv * ev;                                                        \
    float M; WAVEMAX(f, M);                                                   \
    float qs = 126.f * fastrcp(M);                                            \
    int bq = (int)(f*qs + 0.5f);                                              \
    if ((lane & 16) == 0) abm[(WRB) + w*CHS + (jown & 31)] = (unsigned char)bq;\
    if (lane == 0) *(float*)(abm + (WRB) + w*CHS + 32) = M;                   \
    STEP_BARRIER();                                                           \
    if ((lane & 16) == 0) P1[eb + (size_t)(T)*MQ + jown] = __logf(f) + C;     \
    fl = f;                                                                   \
} while(0)

// backward step
#define BSTEP(T, RDB, WRB) do {                                               \
    float ev = evn;                                                           \
    int tn = ((T) > 0) ? (T)-1 : 0;                                           \
    evn = Eb[(size_t)tn*MQ + jown];                                           \
    float Mig = *(const float*)(abm + (RDB) + ig*CHS + 32);                   \
    float c; CMAX(c, Mig);                                                    \
    float invc = fastrcp(c);                                                  \
    float mv; MATVEC8(mv, RDB, Mig);                                          \
    D += __logf(c);                                                           \
    mv *= rsj126 * invc;                                                      \
    float y = mv * ev;                                                        \
    float M; WAVEMAX(y, M);                                                   \
    float qs = 126.f * fastrcp(M);                                            \
    int bq = (int)(y*qs + 0.5f);                                              \
    if ((lane & 16) == 0) abm[(WRB) + w*CHS + (jown & 31)] = (unsigned char)bq;\
    if (lane == 0) *(float*)(abm + (WRB) + w*CHS + 32) = M;                   \
    STEP_BARRIER();                                                           \
    if ((lane & 16) == 0) out[eb + (size_t)(T)*MQ + jown] = __logf(mv) + D;   \
} while(0)

__global__ __launch_bounds__(1024, 1) void k_fwdbwd(
    const unsigned* __restrict__ Aq8, const unsigned* __restrict__ ATq8,
    const float* __restrict__ invA, const float* __restrict__ invT,
    const float* __restrict__ E, const float* __restrict__ initp,
    float* __restrict__ P1, float* __restrict__ out, float* __restrict__ llws)
{
    extern __shared__ __align__(16) unsigned shm[];
    unsigned char* abm = (unsigned char*)shm;
    const int bid = blockIdx.x;                 // 128 blocks
    const int dir = bid & 1, m = (bid >> 1) & 1;
    const int b  = bid >> 2;                    // 0..31
    const int tid = threadIdx.x;                // 1024
    const int w = tid >> 6, lane = tid & 63;    // 16 waves
    const int ig = (lane & 3) | ((lane >> 1) & 12);      // chunk, lane bits {0,1,3,4}
    const int jg = ((lane >> 2) & 1) | ((lane >> 4) & 2);// octet, lane bits {2,5}
    const int r  = (lane & 3) | ((lane >> 1) & 4);       // final col offset, bits {0,1,3}
    const int jo = w*32 + jg*8;                 // octet base
    const int jown = jo + r;                    // owned output column (dup with l^16)

    const unsigned* gQ = (dir ? ATq8 : Aq8) + (size_t)m * (128*MQ);
    const uint4* gQ4 = (const uint4*)gQ;
    const float rsj126 = (dir ? invT : invA)[m*MQ + jown] * (1.f/126.f);
    const size_t eb = ((size_t)(m*MB + b)) * ML * MQ;
    const float* Eb = E + eb;

    // ---- preload i8 A-slice: 32 i (chunk ig) x 8 j (octet) = 16 uint4 = 64 dwords --
    uint4 Ar[16];
    #pragma unroll
    for (int p = 0; p < 8; ++p) {
        Ar[p*2+0] = gQ4[(size_t)(ig*8 + p)*128 + (jo >> 2)];
        Ar[p*2+1] = gQ4[(size_t)(ig*8 + p)*128 + (jo >> 2) + 1];
    }

    if (dir == 0) {
        // ================= forward =================
        float C = 0.f;
        float fl;
        {   // t = 0: f = alpha_0 exactly
            float ev = Eb[jown];
            float f = initp[m*MQ + jown] * ev;
            float M; WAVEMAX(f, M);
            float qs = 126.f * fastrcp(M);
            int bq = (int)(f*qs + 0.5f);
            if ((lane & 16) == 0) abm[AB0 + w*CHS + (jown & 31)] = (unsigned char)bq;
            if (lane == 0) *(float*)(abm + AB0 + w*CHS + 32) = M;
            if ((lane & 16) == 0) P1[eb + jown] = __logf(f);
            fl = f;
            STEP_BARRIER();
        }
        float evn = Eb[MQ + jown];              // prefetch t=1
        FSTEP(1, AB0, AB1);
        #pragma unroll 1
        for (int t = 2; t < ML; t += 2) {
            FSTEP(t,   AB1, AB0);
            FSTEP(t+1, AB0, AB1);
        }
        // loglik = log(sum_j f_last) + C   (mask duplicate lanes)
        float s = (lane & 16) ? 0.f : fl;
        #pragma unroll
        for (int d = 1; d <= 32; d <<= 1) s += __shfl_xor(s, d);
        if (lane == 0) *(float*)(abm + REDB + w*4) = s;
        __syncthreads();
        if (tid == 0) {
            float tot = 0.f;
            #pragma unroll
            for (int k = 0; k < 16; ++k) tot += *(float*)(abm + REDB + k*4);
            float ll = __logf(tot) + C;
            llws[m*MB + b] = ll;
            out[NPOST + m*MB + b] = ll;
        }
    } else {
        // ================= backward =================
        float D = 0.f;
        {   // t = L-1: beta = 1, store y = E[L-1]
            float ev = Eb[(size_t)(ML-1)*MQ + jown];
            float M; WAVEMAX(ev, M);
            float qs = 126.f * fastrcp(M);
            int bq = (int)(ev*qs + 0.5f);
            if ((lane & 16) == 0) abm[AB0 + w*CHS + (jown & 31)] = (unsigned char)bq;
            if (lane == 0) *(float*)(abm + AB0 + w*CHS + 32) = M;
            if ((lane & 16) == 0) out[eb + (size_t)(ML-1)*MQ + jown] = 0.f;
            STEP_BARRIER();
        }
        float evn = Eb[(size_t)(ML-2)*MQ + jown];
        BSTEP(ML-2, AB0, AB1);
        #pragma unroll 1
        for (int t = ML-3; t >= 1; t -= 2) {
            BSTEP(t,   AB1, AB0);
            BSTEP(t-1, AB0, AB1);
        }
    }
}

// ---------------- combine: out = P2(out) + P1 - loglik ----------------
__global__ void k_combine(const float* __restrict__ P1, const float* __restrict__ llws,
                          float* __restrict__ out) {
    size_t idx = ((size_t)blockIdx.x * 256 + threadIdx.x) * 4;
    int mb = (int)(idx >> 18);                  // L*Q = 262144 per (m,b)
    float ll = llws[mb];
    float4 p = *(const float4*)(P1 + idx);
    float4 o = *(const float4*)(out + idx);
    o.x = o.x + p.x - ll;
    o.y = o.y + p.y - ll;
    o.z = o.z + p.z - ll;
    o.w = o.w + p.w - ll;
    *(float4*)(out + idx) = o;
}

extern "C" void kernel_launch(void* const* d_in, const int* in_sizes, int n_in,
                              void* d_out, int out_size, void* d_ws, size_t ws_size,
                              hipStream_t stream) {
    (void)in_sizes; (void)n_in; (void)out_size; (void)ws_size;
    const float* inp   = (const float*)d_in[0];
    const float* trans = (const float*)d_in[1];
    const float* emis  = (const float*)d_in[2];
    const float* initl = (const float*)d_in[3];
    float* out = (float*)d_out;
    float* ws  = (float*)d_ws;

    float*    wsA    = ws + OFF_A;
    unsigned* wsAQ8  = (unsigned*)(ws + OFF_AQ8);
    unsigned* wsATQ8 = (unsigned*)(ws + OFF_ATQ8);
    float*    wsCP   = ws + OFF_CP;
    float*    wsROWM = ws + OFF_ROWM;
    float*    wsSCA  = ws + OFF_SCA;
    float*    wsINVA = ws + OFF_INVA;
    float*    wsSCT  = ws + OFF_SCT;
    float*    wsINVT = ws + OFF_INVT;
    float*    wsB    = ws + OFF_B;
    float*    wsInit = ws + OFF_INIT;
    float*    wsE    = ws + OFF_E;
    float*    wsP1   = ws + OFF_P1;
    float*    wsLL   = ws + OFF_LL;

    (void)hipFuncSetAttribute((const void*)k_fwdbwd,
                              hipFuncAttributeMaxDynamicSharedMemorySize,
                              SHM_DYN);

    k_softmaxA<<<MM*MQ, 256, 0, stream>>>(trans, wsA);
    k_amaxc<<<dim3(16, MM), 512, 0, stream>>>(wsA, wsCP, wsROWM);
    k_amaxr<<<MM, 512, 0, stream>>>(wsCP, wsROWM, wsSCA, wsINVA, wsSCT, wsINVT);
    k_packA8<<<dim3(128, MM), 512, 0, stream>>>(wsA, wsSCA, wsAQ8);
    k_packAT8<<<dim3(8, 8, MM), dim3(64, 4), 0, stream>>>(wsA, wsSCT, wsATQ8);
    k_bprep<<<MM, 512, 0, stream>>>(emis, initl, wsB, wsInit);
    k_ekernel<<<dim3(ML/8, MB, MM), 512, 0, stream>>>(inp, wsB, wsE);
    k_fwdbwd<<<128, 1024, SHM_DYN, stream>>>(wsAQ8, wsATQ8, wsINVA, wsINVT,
                                             wsE, wsInit, wsP1, out, wsLL);
    k_combine<<<NPOST/1024, 256, 0, stream>>>(wsP1, wsLL, out);
}

// Round 8
// 697.373 us; speedup vs baseline: 1.2397x; 1.2397x over previous
//
#include <hip/hip_runtime.h>
#include <math.h>

#define MQ 512           // states q
#define ML 512           // sequence length L
#define MS 26            // symbols
#define MB 32            // batch
#define MM 2             // models
#define NPOST (MM*MB*ML*MQ)   // 16777216

// ws layout (float slots)
#define OFF_A    0                               // MM*MQ*MQ fp32 prob A
#define OFF_AQ8  (OFF_A + MM*MQ*MQ)              // i8-packed A  [m][128 ip][512 j] dwords
#define OFF_ATQ8 (OFF_AQ8 + MM*128*MQ)           // i8-packed AT
#define OFF_CP   (OFF_ATQ8 + MM*128*MQ)          // col partial maxes [m][16][512]
#define OFF_ROWM (OFF_CP + MM*16*MQ)             // row maxes [m][512]
#define OFF_SCA  (OFF_ROWM + MM*MQ)              // 127/colmax
#define OFF_INVA (OFF_SCA + MM*MQ)               // colmax/127
#define OFF_SCT  (OFF_INVA + MM*MQ)              // 127/rowmax
#define OFF_INVT (OFF_SCT + MM*MQ)               // rowmax/127
#define OFF_B    (OFF_INVT + MM*MQ)
#define OFF_INIT (OFF_B + MM*MQ*MS)
#define OFF_E    (OFF_INIT + MM*MQ)
#define OFF_P1   (OFF_E + NPOST)
#define OFF_LL   (OFF_P1 + NPOST)

#if __has_builtin(__builtin_amdgcn_sdot4)
#define SDOT4(a,b,c) __builtin_amdgcn_sdot4((int)(a),(int)(b),(c),false)
#else
static __device__ __forceinline__ int SDOT4(unsigned a, unsigned b, int c){
  #pragma unroll
  for (int k=0;k<4;++k){
    int av = (int)((a >> (8*k)) & 0xffu); av = (av<<24)>>24;
    int bv = (int)((b >> (8*k)) & 0xffu); bv = (bv<<24)>>24;
    c += av*bv;
  }
  return c;
}
#endif

// ---------------- VALU cross-lane primitives (no LDS pipe) ----------------
#if __has_builtin(__builtin_amdgcn_mov_dpp)
#define DPPF(x, ctrl) __uint_as_float((unsigned)__builtin_amdgcn_mov_dpp(      \
    (int)__float_as_uint(x), (ctrl), 0xF, 0xF, true))
#define HAVE_DPP 1
#else
#define HAVE_DPP 0
#endif

#if __has_builtin(__builtin_amdgcn_permlane16_swap)
static __device__ __forceinline__ float pl16crossf(float x, int lane) {
    unsigned xi = __float_as_uint(x);
    auto r = __builtin_amdgcn_permlane16_swap(xi, xi, false, false);
    return __uint_as_float((lane & 16) ? r[0] : r[1]);
}
static __device__ __forceinline__ float pl16maxf(float x) {
    unsigned xi = __float_as_uint(x);
    auto r = __builtin_amdgcn_permlane16_swap(xi, xi, false, false);
    return fmaxf(__uint_as_float(r[0]), __uint_as_float(r[1]));
}
#else
static __device__ __forceinline__ float pl16crossf(float x, int lane) { (void)lane; return __shfl_xor(x, 16); }
static __device__ __forceinline__ float pl16maxf(float x) { return fmaxf(x, __shfl_xor(x, 16)); }
#endif

#if __has_builtin(__builtin_amdgcn_permlane32_swap)
static __device__ __forceinline__ float pl32crossf(float x, int lane) {
    unsigned xi = __float_as_uint(x);
    auto r = __builtin_amdgcn_permlane32_swap(xi, xi, false, false);
    return __uint_as_float((lane & 32) ? r[0] : r[1]);
}
static __device__ __forceinline__ float pl32maxf(float x) {
    unsigned xi = __float_as_uint(x);
    auto r = __builtin_amdgcn_permlane32_swap(xi, xi, false, false);
    return fmaxf(__uint_as_float(r[0]), __uint_as_float(r[1]));
}
#else
static __device__ __forceinline__ float pl32crossf(float x, int lane) { (void)lane; return __shfl_xor(x, 32); }
static __device__ __forceinline__ float pl32maxf(float x) { return fmaxf(x, __shfl_xor(x, 32)); }
#endif

#if HAVE_DPP
static __device__ __forceinline__ float ror8f(float x) { return DPPF(x, 0x128); }
// full-wave max, all-VALU
#define WAVEMAX(X, M) do { float _m = (X);                                    \
  _m = fmaxf(_m, DPPF(_m, 0xB1));   /* xor1 */                                \
  _m = fmaxf(_m, DPPF(_m, 0x4E));   /* xor2 */                                \
  _m = fmaxf(_m, DPPF(_m, 0x124));  /* row_ror:4 */                           \
  _m = fmaxf(_m, DPPF(_m, 0x128));  /* row_ror:8 */                           \
  _m = pl16maxf(_m);                                                          \
  _m = pl32maxf(_m);                                                          \
  M = _m; } while(0)
#else
static __device__ __forceinline__ float ror8f(float x) { return __shfl_xor(x, 8); }
#define WAVEMAX(X, M) { M = (X);                                              \
  _Pragma("unroll") for (int d = 1; d <= 32; d <<= 1)                         \
    M = fmaxf(M, __shfl_xor(M, d)); }
#endif

// ---------------- row softmax of transition logits -> A (prob domain) ----------------
__global__ void k_softmaxA(const float* __restrict__ tl, float* __restrict__ A) {
    int row = blockIdx.x;                       // m*512 + i
    const float* x = tl + (size_t)row * MQ;
    float* y = A + (size_t)row * MQ;
    int tid = threadIdx.x;                      // 256 threads
    float v0 = x[tid], v1 = x[tid + 256];
    float mx = fmaxf(v0, v1);
    #pragma unroll
    for (int d = 32; d >= 1; d >>= 1) mx = fmaxf(mx, __shfl_xor(mx, d));
    __shared__ float sm[4], ss[4];
    int w = tid >> 6;
    if ((tid & 63) == 0) sm[w] = mx;
    __syncthreads();
    mx = fmaxf(fmaxf(sm[0], sm[1]), fmaxf(sm[2], sm[3]));
    float e0 = expf(v0 - mx), e1 = expf(v1 - mx);
    float s = e0 + e1;
    #pragma unroll
    for (int d = 32; d >= 1; d >>= 1) s += __shfl_xor(s, d);
    if ((tid & 63) == 0) ss[w] = s;
    __syncthreads();
    s = ss[0] + ss[1] + ss[2] + ss[3];
    float inv = 1.0f / s;
    y[tid] = e0 * inv;
    y[tid + 256] = e1 * inv;
}

// ---------------- column partial maxes + row maxes of A ----------------
__global__ void k_amaxc(const float* __restrict__ A, float* __restrict__ colpart,
                        float* __restrict__ rowmax) {
    int g = blockIdx.x, m = blockIdx.y;         // 16 x MM
    int tid = threadIdx.x;                      // 512
    const float* Am = A + (size_t)m*MQ*MQ;
    float cm = 0.f;
    for (int r = 0; r < 32; ++r)
        cm = fmaxf(cm, Am[(size_t)(g*32+r)*MQ + tid]);
    colpart[((size_t)m*16 + g)*MQ + tid] = cm;
    int w = tid >> 6, lane = tid & 63;
    for (int k = 0; k < 4; ++k) {
        int row = g*32 + w*4 + k;
        const float* rp = Am + (size_t)row*MQ;
        float rm = 0.f;
        #pragma unroll
        for (int c = 0; c < 8; ++c) rm = fmaxf(rm, rp[lane + 64*c]);
        #pragma unroll
        for (int d = 1; d <= 32; d <<= 1) rm = fmaxf(rm, __shfl_xor(rm, d));
        if (lane == 0) rowmax[m*MQ + row] = rm;
    }
}

// ---------------- finalize scales ----------------
__global__ void k_amaxr(const float* __restrict__ colpart, const float* __restrict__ rowmax,
                        float* __restrict__ scA, float* __restrict__ invA,
                        float* __restrict__ scT, float* __restrict__ invT) {
    int m = blockIdx.x, j = threadIdx.x;        // MM x 512
    float cm = 0.f;
    #pragma unroll
    for (int g = 0; g < 16; ++g) cm = fmaxf(cm, colpart[((size_t)m*16 + g)*MQ + j]);
    scA[m*MQ + j] = 127.f / cm;  invA[m*MQ + j] = cm * (1.f/127.f);
    float rm = rowmax[m*MQ + j];
    scT[m*MQ + j] = 127.f / rm;  invT[m*MQ + j] = rm * (1.f/127.f);
}

// ---------------- pack A -> i8 dwords [m][ip][j], per-column scale ----------------
__global__ void k_packA8(const float* __restrict__ A, const float* __restrict__ sc,
                         unsigned* __restrict__ Aq) {
    int ip = blockIdx.x, m = blockIdx.y, j = threadIdx.x;  // 128 x MM, 512 thr
    const float* Am = A + (size_t)m*MQ*MQ;
    float s = sc[m*MQ + j];
    unsigned d = 0;
    #pragma unroll
    for (int r = 0; r < 4; ++r) {
        int q = (int)(Am[(size_t)(4*ip+r)*MQ + j] * s + 0.5f);
        d |= ((unsigned)q & 0xffu) << (8*r);
    }
    Aq[((size_t)m*128 + ip)*MQ + j] = d;
}

// ---------------- pack AT -> i8 dwords via 64x64 tile, per-row-of-A scale ----------
__global__ void k_packAT8(const float* __restrict__ A, const float* __restrict__ scT,
                          unsigned* __restrict__ ATq) {
    __shared__ float tile[64][65];
    int ipb = blockIdx.x, jjb = blockIdx.y, m = blockIdx.z;  // 8 x 8 x MM
    int tx = threadIdx.x, ty = threadIdx.y;     // (64,4)
    const float* Am = A + (size_t)m*MQ*MQ;
    for (int r = ty; r < 64; r += 4)
        tile[r][tx] = Am[(size_t)(jjb*64 + r)*MQ + ipb*64 + tx];
    __syncthreads();
    float s = scT[m*MQ + jjb*64 + tx];
    for (int ipl = ty; ipl < 16; ipl += 4) {
        unsigned d = 0;
        #pragma unroll
        for (int r = 0; r < 4; ++r) {
            int q = (int)(tile[tx][4*ipl + r] * s + 0.5f);
            d |= ((unsigned)q & 0xffu) << (8*r);
        }
        ATq[((size_t)m*128 + ipb*16 + ipl)*MQ + jjb*64 + tx] = d;
    }
}

// ---------------- emission softmax (B) + init softmax ----------------
__global__ void k_bprep(const float* __restrict__ emis, const float* __restrict__ initl,
                        float* __restrict__ Bmat, float* __restrict__ initp) {
    int m = blockIdx.x;
    int q = threadIdx.x;                        // 512 threads
    const float* er = emis + ((size_t)(m*MQ) + q) * MS;
    float tv[MS];
    float mx = -1e30f;
    #pragma unroll
    for (int s = 0; s < MS; s++) { tv[s] = er[s]; mx = fmaxf(mx, tv[s]); }
    float sum = 0.f;
    #pragma unroll
    for (int s = 0; s < MS; s++) { tv[s] = expf(tv[s] - mx); sum += tv[s]; }
    float inv = 1.f / sum;
    float* bo = Bmat + ((size_t)(m*MQ) + q) * MS;
    #pragma unroll
    for (int s = 0; s < MS; s++) bo[s] = tv[s] * inv;

    __shared__ float red2[8];
    float v = initl[m*MQ + q];
    float mx2 = v;
    #pragma unroll
    for (int d = 32; d >= 1; d >>= 1) mx2 = fmaxf(mx2, __shfl_xor(mx2, d));
    if ((q & 63) == 0) red2[q >> 6] = mx2;
    __syncthreads();
    mx2 = red2[0];
    #pragma unroll
    for (int k = 1; k < 8; k++) mx2 = fmaxf(mx2, red2[k]);
    float e = expf(v - mx2);
    float s2 = e;
    #pragma unroll
    for (int d = 32; d >= 1; d >>= 1) s2 += __shfl_xor(s2, d);
    __syncthreads();
    if ((q & 63) == 0) red2[q >> 6] = s2;
    __syncthreads();
    s2 = 0.f;
    #pragma unroll
    for (int k = 0; k < 8; k++) s2 += red2[k];
    initp[m*MQ + q] = e / s2;
}

// ---------------- E[m,b,l,q] = sum_s inputs[m,b,l,s]*B[m,q,s] + EPS ----------------
__global__ void k_ekernel(const float* __restrict__ inp, const float* __restrict__ Bmat,
                          float* __restrict__ E) {
    int lc = blockIdx.x, b = blockIdx.y, m = blockIdx.z;
    int tid = threadIdx.x;                      // 512
    __shared__ float Bl[MQ * MS];               // 53KB
    __shared__ float xl[8 * MS];
    for (int k = tid; k < MQ * MS; k += 512) Bl[k] = Bmat[(size_t)m * MQ * MS + k];
    int l0 = lc * 8;
    const float* xin = inp + (((size_t)(m*MB + b) * ML + l0) * MS);
    for (int k = tid; k < 8 * MS; k += 512) xl[k] = xin[k];
    __syncthreads();
    float* Eo = E + (((size_t)(m*MB + b) * ML + l0) * MQ);
    const float* br = Bl + tid * MS;
    for (int l = 0; l < 8; l++) {
        float acc = 1e-16f;
        const float* xr = xl + l * MS;
        #pragma unroll
        for (int s = 0; s < MS; s++) acc = fmaf(br[s], xr[s], acc);
        Eo[l * MQ + tid] = acc;
    }
}

// ---------------- fused fwd/bwd: 128 blocks (dir,m,b) x 512 threads, i8 dots ---------
// R8 = R6 (best, 584us) + step-chain diet, numerics bit-identical:
//  (1) scale exchange 7 DS reads -> 5: Mig = wavemax[ig] already distributes the 8
//      wave maxes on lane bits {3,4,5}; c = max over ig via ror8+pl16+pl32 (3 VALU
//      ops) == old MAX8 of two float4 reads.  Deletes 2 b128 DS reads/lane/step.
//  (2) P1/out log+store moved AFTER the step barrier (fills next step's DS wait).
//  (3) issue order: evn global prefetch -> Mig b32 -> alpha b128 -> SDOT block.

#define SHM_DYN 81920               // big dyn-LDS pins 1 block/CU

// LDS byte offsets
#define AB0   0                     // alpha bytes buffer 0: 8 slots x 80 B
#define AB1   640                   // alpha bytes buffer 1
#define SMB0  1280                  // 8 wave maxes (f32), buffer 0
#define SMB1  1312                  // 8 wave maxes (f32), buffer 1
#define REDB  1344                  // final loglik reduce scratch (8 f32)

static __device__ __forceinline__ float fastrcp(float x) {
    float r;
    asm("v_rcp_f32 %0, %1" : "=v"(r) : "v"(x));
    return r;
}

#define DOTQ(P, AD) { u[0]=SDOT4(Ar[(P)*2+0].x,(AD),u[0]); u[1]=SDOT4(Ar[(P)*2+0].y,(AD),u[1]); \
  u[2]=SDOT4(Ar[(P)*2+0].z,(AD),u[2]); u[3]=SDOT4(Ar[(P)*2+0].w,(AD),u[3]);                     \
  u[4]=SDOT4(Ar[(P)*2+1].x,(AD),u[4]); u[5]=SDOT4(Ar[(P)*2+1].y,(AD),u[5]);                     \
  u[6]=SDOT4(Ar[(P)*2+1].z,(AD),u[6]); u[7]=SDOT4(Ar[(P)*2+1].w,(AD),u[7]); }

// int8 matvec + per-chunk scale MIG + all-VALU reduce-scatter (dist 8, 16, 32).
#define MATVEC_F(MV, RDB, MIG) do {                                           \
  int u[8];                                                                   \
  _Pragma("unroll") for (int k=0;k<8;k++) u[k]=0;                             \
  const uint4* av4 = (const uint4*)(abm + (RDB) + ig*80);                     \
  uint4 av0 = av4[0], av1 = av4[1], av2 = av4[2], av3 = av4[3];               \
  DOTQ(0,  av0.x) DOTQ(1,  av0.y) DOTQ(2,  av0.z) DOTQ(3,  av0.w)             \
  DOTQ(4,  av1.x) DOTQ(5,  av1.y) DOTQ(6,  av1.z) DOTQ(7,  av1.w)             \
  DOTQ(8,  av2.x) DOTQ(9,  av2.y) DOTQ(10, av2.z) DOTQ(11, av2.w)             \
  DOTQ(12, av3.x) DOTQ(13, av3.y) DOTQ(14, av3.z) DOTQ(15, av3.w)             \
  float fu[8];                                                                \
  _Pragma("unroll") for (int k=0;k<8;k++) fu[k] = (float)u[k] * (MIG);        \
  const int h1 = ig & 1, h2 = (ig >> 1) & 1, h4 = (ig >> 2) & 1;              \
  float w4v[4];                                                               \
  _Pragma("unroll") for (int k=0;k<4;k++){                                    \
    float mi = h1 ? fu[2*k+1] : fu[2*k];                                      \
    float ot = h1 ? fu[2*k]   : fu[2*k+1];                                    \
    w4v[k] = mi + ror8f(ot); }                                                \
  float w2v[2];                                                               \
  _Pragma("unroll") for (int k=0;k<2;k++){                                    \
    float mi = h2 ? w4v[2*k+1] : w4v[2*k];                                    \
    float ot = h2 ? w4v[2*k]   : w4v[2*k+1];                                  \
    w2v[k] = mi + pl16crossf(ot, lane); }                                     \
  { float mi = h4 ? w2v[1] : w2v[0];                                          \
    float ot = h4 ? w2v[0] : w2v[1];                                          \
    MV = mi + pl32crossf(ot, lane); }                                         \
} while(0)

// lgkmcnt-only barrier: LDS writes visible, global stores NOT drained
#define STEP_BARRIER() asm volatile("s_waitcnt lgkmcnt(0)\n\ts_barrier" ::: "memory")

// forward step, compile-time buffers; P1 log+store after the barrier.
// c = max over ig of Mig (3 VALU xor-maxes) — identical value to old MAX8.
#define FSTEP(T, RDB, RDS, WRB, WRS) do {                                     \
    float ev = evn;                                                           \
    int tn = ((T)+1 < ML) ? (T)+1 : ML-1;                                     \
    evn = Eb[(size_t)tn*MQ + jown];                                           \
    float Mig = *(const float*)(abm + (RDS) + ig*4);                          \
    float bf; MATVEC_F(bf, (RDB), Mig);                                       \
    float c = Mig;                                                            \
    c = fmaxf(c, ror8f(c)); c = pl16maxf(c); c = pl32maxf(c);                 \
    float invc = fastrcp(c);                                                  \
    C += __logf(c);                                                           \
    float mv = bf * (rsj126 * invc);                                          \
    float f = mv * ev;                                                        \
    float M; WAVEMAX(f, M);                                                   \
    float qs = 126.f * fastrcp(M);                                            \
    abm[(WRB) + wslot] = (unsigned char)(int)(f*qs + 0.5f);                   \
    if (lane == 0) *(float*)(abm + (WRS) + w*4) = M;                          \
    STEP_BARRIER();                                                           \
    P1[eb + (size_t)(T)*MQ + jown] = __logf(f) + C;                           \
    fl = f;                                                                   \
} while(0)

// backward step
#define BSTEP(T, RDB, RDS, WRB, WRS) do {                                     \
    float ev = evn;                                                           \
    int tn = ((T) > 0) ? (T)-1 : 0;                                           \
    evn = Eb[(size_t)tn*MQ + jown];                                           \
    float Mig = *(const float*)(abm + (RDS) + ig*4);                          \
    float bf; MATVEC_F(bf, (RDB), Mig);                                       \
    float c = Mig;                                                            \
    c = fmaxf(c, ror8f(c)); c = pl16maxf(c); c = pl32maxf(c);                 \
    float invc = fastrcp(c);                                                  \
    D += __logf(c);                                                           \
    float mv = bf * (rsj126 * invc);                                          \
    float y = mv * ev;                                                        \
    float M; WAVEMAX(y, M);                                                   \
    float qs = 126.f * fastrcp(M);                                            \
    abm[(WRB) + wslot] = (unsigned char)(int)(y*qs + 0.5f);                   \
    if (lane == 0) *(float*)(abm + (WRS) + w*4) = M;                          \
    STEP_BARRIER();                                                           \
    out[eb + (size_t)(T)*MQ + jown] = __logf(mv) + D;                         \
} while(0)

__global__ __launch_bounds__(512, 1) void k_fwdbwd(
    const unsigned* __restrict__ Aq8, const unsigned* __restrict__ ATq8,
    const float* __restrict__ invA, const float* __restrict__ invT,
    const float* __restrict__ E, const float* __restrict__ initp,
    float* __restrict__ P1, float* __restrict__ out, float* __restrict__ llws)
{
    extern __shared__ __align__(16) unsigned shm[];
    unsigned char* abm = (unsigned char*)shm;
    const int bid = blockIdx.x;                 // 128 blocks
    const int dir = bid & 1, m = (bid >> 1) & 1;
    const int b  = bid >> 2;                    // 0..31
    const int tid = threadIdx.x;
    const int w = tid >> 6, lane = tid & 63;
    const int ig = lane >> 3, jg = lane & 7;
    const int jbase = w*64 + jg*8;
    const int jown = jbase + ig;
    const int wslot = (jown>>6)*80 + (jown&63); // byte pos of this lane's alpha slot

    const unsigned* gQ = (dir ? ATq8 : Aq8) + (size_t)m * (128*MQ);
    const uint4* gQ4 = (const uint4*)gQ;
    const float rsj126 = (dir ? invT : invA)[m*MQ + jown] * (1.f/126.f);
    const size_t eb = ((size_t)(m*MB + b)) * ML * MQ;
    const float* Eb = E + eb;

    // ---- preload i8 A-slice: 32 uint4 = 128 regs ----
    uint4 Ar[32];
    #pragma unroll
    for (int p = 0; p < 16; ++p) {
        Ar[p*2+0] = gQ4[(size_t)(ig*16 + p)*128 + (jbase>>2)];
        Ar[p*2+1] = gQ4[(size_t)(ig*16 + p)*128 + (jbase>>2) + 1];
    }

    if (dir == 0) {
        // ================= forward =================
        float C = 0.f;
        float fl;
        {   // t = 0: f = alpha_0 exactly
            float ev = Eb[jown];
            float f = initp[m*MQ + jown] * ev;
            float M; WAVEMAX(f, M);
            float qs = 126.f * fastrcp(M);
            abm[AB0 + wslot] = (unsigned char)(int)(f*qs + 0.5f);
            if (lane == 0) *(float*)(abm + SMB0 + w*4) = M;
            P1[eb + jown] = __logf(f);
            fl = f;
            STEP_BARRIER();
        }
        float evn = Eb[MQ + jown];              // prefetch t=1
        FSTEP(1, AB0, SMB0, AB1, SMB1);
        #pragma unroll 1
        for (int t = 2; t < ML; t += 2) {
            FSTEP(t,   AB1, SMB1, AB0, SMB0);
            FSTEP(t+1, AB0, SMB0, AB1, SMB1);
        }
        // loglik = log(sum_j f_last) + C
        float s = fl;
        #pragma unroll
        for (int d = 1; d <= 32; d <<= 1) s += __shfl_xor(s, d);
        if (lane == 0) *(float*)(abm + REDB + w*4) = s;
        __syncthreads();
        if (tid == 0) {
            float tot = 0.f;
            #pragma unroll
            for (int k = 0; k < 8; ++k) tot += *(float*)(abm + REDB + k*4);
            float ll = __logf(tot) + C;
            llws[m*MB + b] = ll;
            out[NPOST + m*MB + b] = ll;
        }
    } else {
        // ================= backward =================
        float D = 0.f;
        {   // t = L-1: beta = 1, store y = E[L-1]
            float ev = Eb[(size_t)(ML-1)*MQ + jown];
            float M; WAVEMAX(ev, M);
            float qs = 126.f * fastrcp(M);
            abm[AB0 + wslot] = (unsigned char)(int)(ev*qs + 0.5f);
            if (lane == 0) *(float*)(abm + SMB0 + w*4) = M;
            out[eb + (size_t)(ML-1)*MQ + jown] = 0.f;
            STEP_BARRIER();
        }
        float evn = Eb[(size_t)(ML-2)*MQ + jown];
        BSTEP(ML-2, AB0, SMB0, AB1, SMB1);
        #pragma unroll 1
        for (int t = ML-3; t >= 1; t -= 2) {
            BSTEP(t,   AB1, SMB1, AB0, SMB0);
            BSTEP(t-1, AB0, SMB0, AB1, SMB1);
        }
    }
}

// ---------------- combine: out = P2(out) + P1 - loglik ----------------
__global__ void k_combine(const float* __restrict__ P1, const float* __restrict__ llws,
                          float* __restrict__ out) {
    size_t idx = ((size_t)blockIdx.x * 256 + threadIdx.x) * 4;
    int mb = (int)(idx >> 18);                  // L*Q = 262144 per (m,b)
    float ll = llws[mb];
    float4 p = *(const float4*)(P1 + idx);
    float4 o = *(const float4*)(out + idx);
    o.x = o.x + p.x - ll;
    o.y = o.y + p.y - ll;
    o.z = o.z + p.z - ll;
    o.w = o.w + p.w - ll;
    *(float4*)(out + idx) = o;
}

extern "C" void kernel_launch(void* const* d_in, const int* in_sizes, int n_in,
                              void* d_out, int out_size, void* d_ws, size_t ws_size,
                              hipStream_t stream) {
    (void)in_sizes; (void)n_in; (void)out_size; (void)ws_size;
    const float* inp   = (const float*)d_in[0];
    const float* trans = (const float*)d_in[1];
    const float* emis  = (const float*)d_in[2];
    const float* initl = (const float*)d_in[3];
    float* out = (float*)d_out;
    float* ws  = (float*)d_ws;

    float*    wsA    = ws + OFF_A;
    unsigned* wsAQ8  = (unsigned*)(ws + OFF_AQ8);
    unsigned* wsATQ8 = (unsigned*)(ws + OFF_ATQ8);
    float*    wsCP   = ws + OFF_CP;
    float*    wsROWM = ws + OFF_ROWM;
    float*    wsSCA  = ws + OFF_SCA;
    float*    wsINVA = ws + OFF_INVA;
    float*    wsSCT  = ws + OFF_SCT;
    float*    wsINVT = ws + OFF_INVT;
    float*    wsB    = ws + OFF_B;
    float*    wsInit = ws + OFF_INIT;
    float*    wsE    = ws + OFF_E;
    float*    wsP1   = ws + OFF_P1;
    float*    wsLL   = ws + OFF_LL;

    (void)hipFuncSetAttribute((const void*)k_fwdbwd,
                              hipFuncAttributeMaxDynamicSharedMemorySize,
                              SHM_DYN);

    k_softmaxA<<<MM*MQ, 256, 0, stream>>>(trans, wsA);
    k_amaxc<<<dim3(16, MM), 512, 0, stream>>>(wsA, wsCP, wsROWM);
    k_amaxr<<<MM, 512, 0, stream>>>(wsCP, wsROWM, wsSCA, wsINVA, wsSCT, wsINVT);
    k_packA8<<<dim3(128, MM), 512, 0, stream>>>(wsA, wsSCA, wsAQ8);
    k_packAT8<<<dim3(8, 8, MM), dim3(64, 4), 0, stream>>>(wsA, wsSCT, wsATQ8);
    k_bprep<<<MM, 512, 0, stream>>>(emis, initl, wsB, wsInit);
    k_ekernel<<<dim3(ML/8, MB, MM), 512, 0, stream>>>(inp, wsB, wsE);
    k_fwdbwd<<<128, 512, SHM_DYN, stream>>>(wsAQ8, wsATQ8, wsINVA, wsINVT,
                                            wsE, wsInit, wsP1, out, wsLL);
    k_combine<<<NPOST/1024, 256, 0, stream>>>(wsP1, wsLL, out);
}